// Round 12
// baseline (295.947 us; speedup 1.0000x reference)
//
#include <hip/hip_runtime.h>
#include <stdint.h>

// MultiHeadAttention: B=2, S=2048, D=1024, H=16, Dh=64. fp32 in/out, bf16 MFMA inside.
// R19: two independent changes.
//  1) attn KVBLK 128->256: halves barrier-pairs (16->8), doubles prefetch depth
//     (kv[4]/vv[4] in flight). LDS 64KB (Ks 32 + Vs 32; merge overlays 34);
//     occupancy unchanged (grid-limited 2 blocks/CU). Vs chunk index is 5-bit:
//     swizzle XORs low 4 bits only: pos = (c&16) | ((c&15)^(row&15)).
//  2) gemm2 64x64 -> 128x64: MFMA:ds_read per ks 8:6 vs 4:4, 2x MFMA per barrier,
//     at 2 blocks/CU (vs 4). Tests per-block efficiency vs TLP for the O-proj.
// Carried: XCD swizzle everywhere, Q pre-scale, raw v_exp_f32, v_perm P-pack,
// fused V-transpose, Q-direct fragment loads.

typedef unsigned short u16;
typedef short s16x8 __attribute__((ext_vector_type(8)));   // 8 bf16 (4 VGPR)
typedef short s16x4 __attribute__((ext_vector_type(4)));   // 4 bf16 (2 VGPR)
typedef float f32x4 __attribute__((ext_vector_type(4)));
typedef u16 u16x4 __attribute__((ext_vector_type(4)));

#define S_LEN 2048
#define DMODEL 1024
#define LOG2E 1.44269504088896340736f

__device__ __forceinline__ u16 f2bf(float f) {
  union { float f; uint32_t u; } v; v.f = f;
  return (u16)((v.u + 0x8000u) >> 16);
}

__device__ __forceinline__ s16x8 ld8f(const float* s) {  // 8 fp32 -> 8 bf16
  f32x4 a = *(const f32x4*)s;
  f32x4 b = *(const f32x4*)(s + 4);
  s16x8 r;
  r[0] = (short)f2bf(a[0]); r[1] = (short)f2bf(a[1]);
  r[2] = (short)f2bf(a[2]); r[3] = (short)f2bf(a[3]);
  r[4] = (short)f2bf(b[0]); r[5] = (short)f2bf(b[1]);
  r[6] = (short)f2bf(b[2]); r[7] = (short)f2bf(b[3]);
  return r;
}

// async global->LDS, 16B/lane; HW scatters lane i to ldsbase + i*16
__device__ __forceinline__ void gl2lds16(const u16* g, u16* l) {
  __builtin_amdgcn_global_load_lds(
      (const __attribute__((address_space(1))) uint32_t*)g,
      (__attribute__((address_space(3))) uint32_t*)l, 16, 0, 0);
}

// ---------------------------------------------------------------------------
// fp32 -> bf16 conversion: 4 weights (1M elem) + 3 activations (4.19M elem).
// ---------------------------------------------------------------------------
struct Cvt7 { const float* s[7]; u16* d[7]; int n[7]; };

__global__ __launch_bounds__(256) void cvt7(Cvt7 p) {
  const int z = blockIdx.y;
  const int idx = blockIdx.x * 256 + threadIdx.x;
  if (idx * 8 < p.n[z])
    *(s16x8*)(p.d[z] + (size_t)idx * 8) = ld8f(p.s[z] + (size_t)idx * 8);
}

// ---------------------------------------------------------------------------
// GEMM: C[M,N] = (A[M,K] @ W[N,K]^T + bias[N]) * scl; A,W bf16, bias fp32.
// Template: BM x BN tile (BK=64 fixed), 4 waves as 2x2 of (BM/2 x BN/2).
// OUT_F32: fp32 C (O projection). VT: z==2 writes transposed bf16 to p.vt.
// XCD swizzle: lid = (w&7)*(nwg/8) + w/8 groups contiguous bm-rows per XCD.
// ---------------------------------------------------------------------------
struct GemmBatch {
  const u16* A[3]; const u16* W[3]; const float* Bv[3]; void* C[3];
  u16* vt;       // VT destination: Vt[(b*16+h)*64+dh][s], row stride S_LEN
  float scl[3];  // epilogue scale (fp32, applied before f2bf round)
};

template <int BM, int BN, bool OUT_F32, bool VT>
__global__ __launch_bounds__(256) void gemm_bt(GemmBatch p, int M, int N, int K) {
  static_assert(!VT || BM == 128, "VT epilogue assumes BM=128 (batch arith)");
  constexpr int MI = BM / 32, NJ = BN / 32;   // fragment repeats per wave
  constexpr int TS = BM + 8;                  // VT transpose stride (u16), 16B-aligned
  constexpr int AB = BM * 64 + BN * 64;
  constexpr int TB = VT ? BN * TS : 0;
  constexpr int SM = AB > TB ? AB : TB;
  __shared__ u16 smem[SM];
  u16* const As = smem;
  u16* const Ws = smem + BM * 64;

  const int z = blockIdx.z;
  const u16* __restrict__ A      = p.A[z];
  const u16* __restrict__ W      = p.W[z];
  const float* __restrict__ bias = p.Bv[z];
  const float scl = p.scl[z];

  const int tid = threadIdx.x;
  const int wave = tid >> 6, lane = tid & 63;
  const int quad = lane >> 4, l16 = lane & 15;

  // XCD-aware bijective swizzle (nwg divisible by 8 for all our grids)
  const int nwg = gridDim.x * gridDim.y;
  const int w = blockIdx.x + gridDim.x * blockIdx.y;
  const int lid = (w & 7) * (nwg >> 3) + (w >> 3);
  const int bm = (lid / gridDim.x) * BM, bn = (lid % gridDim.x) * BN;

  const int wr = (wave >> 1) * (BM / 2), wc = (wave & 1) * (BN / 2);
  const int sr8 = lane >> 3;
  const int slc = (lane & 7) ^ sr8;           // logical k-chunk to fetch
  const int srow = wave * 8 + sr8;            // row within 32-row stripe

  f32x4 acc[MI][NJ];
#pragma unroll
  for (int i = 0; i < MI; i++)
#pragma unroll
    for (int j = 0; j < NJ; j++) acc[i][j] = {0.f, 0.f, 0.f, 0.f};

  const u16* Ab = A + (size_t)bm * K;
  const u16* Wb = W + (size_t)bn * K;

  for (int kt = 0; kt < K; kt += 64) {
    __syncthreads();  // previous iteration's LDS reads complete
#pragma unroll
    for (int i = 0; i < MI; i++)
      gl2lds16(Ab + (size_t)(i * 32 + srow) * K + kt + slc * 8,
               &As[(i * 32 + wave * 8) * 64]);
#pragma unroll
    for (int i = 0; i < NJ; i++)
      gl2lds16(Wb + (size_t)(i * 32 + srow) * K + kt + slc * 8,
               &Ws[(i * 32 + wave * 8) * 64]);
    __syncthreads();  // drains vmcnt (async loads) + LDS visible

#pragma unroll
    for (int ks = 0; ks < 2; ks++) {
      const int ch = ks * 4 + quad;  // logical chunk of this fragment
      s16x8 a[MI], b[NJ];
#pragma unroll
      for (int t = 0; t < MI; t++)
        a[t] = *(const s16x8*)&As[(wr + t * 16 + l16) * 64 + ((ch ^ (l16 & 7)) << 3)];
#pragma unroll
      for (int t = 0; t < NJ; t++)
        b[t] = *(const s16x8*)&Ws[(wc + t * 16 + l16) * 64 + ((ch ^ (l16 & 7)) << 3)];
#pragma unroll
      for (int i = 0; i < MI; i++)
#pragma unroll
        for (int j = 0; j < NJ; j++)
          acc[i][j] = __builtin_amdgcn_mfma_f32_16x16x32_bf16(a[i], b[j], acc[i][j], 0, 0, 0);
    }
  }

  if (VT && z == 2) {
    // ---- fused V transpose: acc -> LDS [col][row] -> Vt[d-row][s] ----
    __syncthreads();               // all waves done reading As/Ws
    u16* const T = smem;           // [BN][TS]
#pragma unroll
    for (int j = 0; j < NJ; j++) {
      const int c = wc + j * 16 + l16;
      const float bv = bias[bn + c];
#pragma unroll
      for (int i = 0; i < MI; i++) {
        const int r0 = wr + i * 16 + quad * 4;
        u16x4 t4;
#pragma unroll
        for (int r = 0; r < 4; r++) t4[r] = f2bf((acc[i][j][r] + bv) * scl);
        *(u16x4*)&T[c * TS + r0] = t4;
      }
    }
    __syncthreads();
    // copy out: SEG threads per column, run = BM/SEG contiguous s per thread
    constexpr int SEG = 256 / BN;            // 2 (BN=128) or 4 (BN=64)
    constexpr int RUN = BM / SEG;            // 64 or 32
    const int c = tid / SEG, seg = tid % SEG;
    const int b_ = bm >> 11;                 // batch (2048 rows each, 128 | 2048)
    const int sb = (bm & 2047) + seg * RUN;  // s within batch
    u16* dst = p.vt + (size_t)(b_ * 1024 + bn + c) * S_LEN + sb;
    const u16* srcT = &T[c * TS + seg * RUN];
#pragma unroll
    for (int k = 0; k < RUN / 8; k++)
      *(s16x8*)(dst + k * 8) = *(const s16x8*)(srcT + k * 8);
  } else {
    // epilogue: C/D layout row = quad*4 + reg, col = lane&15
#pragma unroll
    for (int j = 0; j < NJ; j++) {
      const int col = bn + wc + j * 16 + l16;
      const float bv = bias[col];
#pragma unroll
      for (int i = 0; i < MI; i++) {
        const int row0 = bm + wr + i * 16 + quad * 4;
#pragma unroll
        for (int r = 0; r < 4; r++) {
          const float val = (acc[i][j][r] + bv) * scl;
          if (OUT_F32)
            ((float*)p.C[z])[(size_t)(row0 + r) * N + col] = val;
          else
            ((u16*)p.C[z])[(size_t)(row0 + r) * N + col] = f2bf(val);
        }
      }
    }
  }
}

// ---------------------------------------------------------------------------
// Flash attention R19: KVBLK=256 (8 barrier-pairs instead of 16). 512 threads =
// 8 waves = 4 q-tiles(32 rows) x 2 kv-halves(128 kv). LDS 64KB: Ks[256][64] +
// Vs[64][256]; merge (34KB) overlays. Q fragments direct from global. Grid
// (16,32) with XCD swizzle (4 bh/XCD, K/V L2-resident).
// ---------------------------------------------------------------------------
__global__ __launch_bounds__(512, 4) void attn_kernel(const u16* __restrict__ Qp,
                                                      const u16* __restrict__ Kp,
                                                      const u16* __restrict__ Vt,
                                                      u16* __restrict__ AO) {
  __shared__ u16 smem[32768];    // 64 KB
  u16* const Ks = smem;          // [kv:256][d:64]  32 KB, 8-chunk XOR swizzle
  u16* const Vs = smem + 16384;  // [d:64][kv:256]  32 KB, 5-bit chunk, low-4 XOR

  const int tid = threadIdx.x;
  const int wave = tid >> 6, lane = tid & 63;
  const int quad = lane >> 4, l16 = lane & 15;

  // XCD swizzle: w = x + 16y, nwg=512 -> 64 lids/XCD -> bh in [4j,4j+4)
  const int w = blockIdx.x + gridDim.x * blockIdx.y;
  const int lid = (w & 7) * 64 + (w >> 3);
  const int bh = lid >> 4, b = bh >> 4, h = bh & 15;
  const int s0 = (lid & 15) * 128;

  const int qw = wave & 3;        // q-tile index (32 rows each)
  const int kvh = wave >> 2;      // kv half (128 kv rows each)

  const int sr = tid >> 3, sc8 = tid & 7;     // K staging: row base, chunk
  const int sxor = (sc8 ^ (sr & 7)) << 3;
  const int vr = tid >> 4, vc = tid & 15;     // V staging: d-row base, chunk base
  const int vx = vc ^ (vr & 15);              // low-4 swizzled chunk

  // ---- Q fragments: direct global load ----
  s16x8 aq[2][2];  // [ks][rt]
#pragma unroll
  for (int ks = 0; ks < 2; ks++)
#pragma unroll
    for (int rt = 0; rt < 2; rt++) {
      const int row = qw * 32 + rt * 16 + l16;
      const int ch = ks * 4 + quad;
      aq[ks][rt] = *(const s16x8*)(Qp + (size_t)(b * S_LEN + s0 + row) * DMODEL + h * 64 + ch * 8);
    }

  // ---- K/V register prefetch for kt=0 ----
  s16x8 kv[4], vv[4];
#pragma unroll
  for (int i = 0; i < 4; i++)
    kv[i] = *(const s16x8*)(Kp + (size_t)(b * S_LEN + i * 64 + sr) * DMODEL + h * 64 + sc8 * 8);
#pragma unroll
  for (int i = 0; i < 4; i++)
    vv[i] = *(const s16x8*)(Vt + (size_t)(bh * 64 + (i & 1) * 32 + vr) * S_LEN + (i >> 1) * 128 + vc * 8);

  f32x4 o[2][4];
  float l_r[2] = {0.f, 0.f};
#pragma unroll
  for (int rt = 0; rt < 2; rt++)
#pragma unroll
    for (int dt = 0; dt < 4; dt++) o[rt][dt] = {0.f, 0.f, 0.f, 0.f};

  const f32x4 zf = {0.f, 0.f, 0.f, 0.f};

  for (int kt = 0; kt < S_LEN; kt += 256) {
    __syncthreads();
#pragma unroll
    for (int i = 0; i < 4; i++)
      *(s16x8*)&Ks[(i * 64 + sr) * 64 + sxor] = kv[i];
#pragma unroll
    for (int i = 0; i < 4; i++)
      *(s16x8*)&Vs[((i & 1) * 32 + vr) * 256 + (((i >> 1) * 16 + vx) << 3)] = vv[i];
    __syncthreads();

    if (kt + 256 < S_LEN) {
      const int k2 = kt + 256;
#pragma unroll
      for (int i = 0; i < 4; i++)
        kv[i] = *(const s16x8*)(Kp + (size_t)(b * S_LEN + k2 + i * 64 + sr) * DMODEL + h * 64 + sc8 * 8);
#pragma unroll
      for (int i = 0; i < 4; i++)
        vv[i] = *(const s16x8*)(Vt + (size_t)(bh * 64 + (i & 1) * 32 + vr) * S_LEN + k2 + (i >> 1) * 128 + vc * 8);
    }

    // this wave's kv half: rows kvh*128 .. +127 (8 subtiles of 16)
#pragma unroll
    for (int kvt = 0; kvt < 8; kvt++) {
      const int krow = kvh * 128 + kvt * 16 + l16;   // krow&7 == l16&7
      s16x8 ak0 = *(const s16x8*)&Ks[krow * 64 + (((0 + quad) ^ (l16 & 7)) << 3)];
      s16x8 ak1 = *(const s16x8*)&Ks[krow * 64 + (((4 + quad) ^ (l16 & 7)) << 3)];

      s16x4 pf[2];
#pragma unroll
      for (int rt = 0; rt < 2; rt++) {
        f32x4 sA;
        sA = __builtin_amdgcn_mfma_f32_16x16x32_bf16(ak0, aq[0][rt], zf, 0, 0, 0);
        sA = __builtin_amdgcn_mfma_f32_16x16x32_bf16(ak1, aq[1][rt], sA, 0, 0, 0);

        union { float f; uint32_t u; } e0, e1, e2, e3;
        e0.f = __builtin_amdgcn_exp2f(sA[0]);
        e1.f = __builtin_amdgcn_exp2f(sA[1]);
        e2.f = __builtin_amdgcn_exp2f(sA[2]);
        e3.f = __builtin_amdgcn_exp2f(sA[3]);
        l_r[rt] += (((e0.f + e1.f) + e2.f) + e3.f);

        union { uint32_t u[2]; s16x4 v; } pk;
        pk.u[0] = __builtin_amdgcn_perm(e1.u + 0x8000u, e0.u + 0x8000u, 0x07060302u);
        pk.u[1] = __builtin_amdgcn_perm(e3.u + 0x8000u, e2.u + 0x8000u, 0x07060302u);
        pf[rt] = pk.v;
      }

      // V chunk: 5-bit index, low-4 swizzled against row (row&15 == l16)
      const int ch = kvh * 16 + kvt * 2 + (quad >> 1);
      const int chp = (ch & 16) | ((ch & 15) ^ l16);
#pragma unroll
      for (int dt = 0; dt < 4; dt++) {
        const int row = dt * 16 + l16;
        s16x4 bv = *(const s16x4*)&Vs[row * 256 + (chp << 3) + (quad & 1) * 4];
        o[0][dt] = __builtin_amdgcn_mfma_f32_16x16x16bf16_1k(pf[0], bv, o[0][dt], 0, 0, 0);
        o[1][dt] = __builtin_amdgcn_mfma_f32_16x16x16bf16_1k(pf[1], bv, o[1][dt], 0, 0, 0);
      }
    }
  }

  // intra-wave l reduction (sum over quads -> value depends on l16 only)
#pragma unroll
  for (int rt = 0; rt < 2; rt++) {
    l_r[rt] += __shfl_xor(l_r[rt], 16);
    l_r[rt] += __shfl_xor(l_r[rt], 32);
  }

  // ---- cross-half merge: waves 4..7 dump O/l into reused staging LDS ----
  __syncthreads();  // all LDS reads of last ktile complete
  f32x4* const mrgO = (f32x4*)smem;            // [rt*4+dt][w*64+lane], 32 KB
  float* const mrgL = (float*)smem + 8192;     // [rt][w*64+lane], 2 KB @ 32 KB
  if (wave >= 4) {
    const int w4 = wave - 4;
#pragma unroll
    for (int rt = 0; rt < 2; rt++) {
#pragma unroll
      for (int dt = 0; dt < 4; dt++)
        mrgO[(rt * 4 + dt) * 256 + w4 * 64 + lane] = o[rt][dt];
      mrgL[rt * 256 + w4 * 64 + lane] = l_r[rt];
    }
  }
  __syncthreads();
  if (wave < 4) {
#pragma unroll
    for (int rt = 0; rt < 2; rt++) {
#pragma unroll
      for (int dt = 0; dt < 4; dt++) {
        f32x4 ov = mrgO[(rt * 4 + dt) * 256 + wave * 64 + lane];
        o[rt][dt] += ov;
      }
      l_r[rt] += mrgL[rt * 256 + wave * 64 + lane];
    }
#pragma unroll
    for (int rt = 0; rt < 2; rt++) {
#pragma unroll
      for (int r = 0; r < 4; r++) {
        const float linv = 1.f / __shfl(l_r[rt], quad * 4 + r);
        const int row = s0 + qw * 32 + rt * 16 + quad * 4 + r;
#pragma unroll
        for (int dt = 0; dt < 4; dt++)
          AO[(size_t)(b * S_LEN + row) * DMODEL + h * 64 + dt * 16 + l16] =
              f2bf(o[rt][dt][r] * linv);
      }
    }
  }
}

// ---------------------------------------------------------------------------
extern "C" void kernel_launch(void* const* d_in, const int* in_sizes, int n_in,
                              void* d_out, int out_size, void* d_ws, size_t ws_size,
                              hipStream_t stream) {
  const float* query = (const float*)d_in[0];
  const float* key_  = (const float*)d_in[1];
  const float* value = (const float*)d_in[2];
  const float* W_q = (const float*)d_in[3];
  const float* b_q = (const float*)d_in[4];
  const float* W_k = (const float*)d_in[5];
  const float* b_k = (const float*)d_in[6];
  const float* W_v = (const float*)d_in[7];
  const float* b_v = (const float*)d_in[8];
  const float* W_o = (const float*)d_in[9];
  const float* b_o = (const float*)d_in[10];
  float* out = (float*)d_out;

  const int M = 2 * S_LEN;  // 4096
  const int N = DMODEL, K = DMODEL;
  const size_t WSZ = (size_t)DMODEL * DMODEL;   // 1,048,576
  const size_t SZ  = (size_t)M * DMODEL;        // 4,194,304

  u16* Wqb = (u16*)d_ws;         // 4 bf16 weights
  u16* Wkb = Wqb + WSZ;
  u16* Wvb = Wkb + WSZ;
  u16* Wob = Wvb + WSZ;
  u16* Qa  = Wob + WSZ;          // bf16 inputs (dead after QKV GEMM)
  u16* Ka  = Qa + SZ;
  u16* Va  = Ka + SZ;
  u16* Qp  = Va + SZ;            // projections
  u16* Kp  = Qp + SZ;
  u16* Vt  = Kp + SZ;            // [B,H,Dh,S] -- written directly by V-GEMM (VT path)
  u16* AO  = Qp;                 // aliases Qp (per-block disjoint read->write)

  Cvt7 cw;
  cw.s[0] = W_q;   cw.d[0] = Wqb; cw.n[0] = (int)WSZ;
  cw.s[1] = W_k;   cw.d[1] = Wkb; cw.n[1] = (int)WSZ;
  cw.s[2] = W_v;   cw.d[2] = Wvb; cw.n[2] = (int)WSZ;
  cw.s[3] = W_o;   cw.d[3] = Wob; cw.n[3] = (int)WSZ;
  cw.s[4] = query; cw.d[4] = Qa;  cw.n[4] = (int)SZ;
  cw.s[5] = key_;  cw.d[5] = Ka;  cw.n[5] = (int)SZ;
  cw.s[6] = value; cw.d[6] = Va;  cw.n[6] = (int)SZ;
  cvt7<<<dim3((int)(SZ / 2048), 7), 256, 0, stream>>>(cw);

  GemmBatch p1;
  p1.A[0] = Qa; p1.W[0] = Wqb; p1.Bv[0] = b_q; p1.C[0] = Qp;
  p1.A[1] = Ka; p1.W[1] = Wkb; p1.Bv[1] = b_k; p1.C[1] = Kp;
  p1.A[2] = Va; p1.W[2] = Wvb; p1.Bv[2] = b_v; p1.C[2] = Vt;  // unused (VT path)
  p1.vt = Vt;
  p1.scl[0] = 0.03125f * LOG2E;  // d_model^-0.5 * log2(e) folded into Q (fp32)
  p1.scl[1] = 1.0f;
  p1.scl[2] = 1.0f;
  gemm_bt<128, 64, false, true><<<dim3(N / 64, M / 128, 3), 256, 0, stream>>>(p1, M, N, K);

  attn_kernel<<<dim3(S_LEN / 128, 32), 512, 0, stream>>>(Qp, Kp, Vt, AO);

  GemmBatch p2;
  p2.A[0] = AO; p2.W[0] = Wob; p2.Bv[0] = b_o; p2.C[0] = out;
  p2.A[1] = AO; p2.W[1] = Wob; p2.Bv[1] = b_o; p2.C[1] = out;
  p2.A[2] = AO; p2.W[2] = Wob; p2.Bv[2] = b_o; p2.C[2] = out;
  p2.vt = nullptr;
  p2.scl[0] = 1.0f; p2.scl[1] = 1.0f; p2.scl[2] = 1.0f;
  gemm_bt<128, 64, true, false><<<dim3(N / 64, M / 128, 1), 256, 0, stream>>>(p2, M, N, K);
}

// Round 13
// 224.448 us; speedup vs baseline: 1.3186x; 1.3186x over previous
//
#include <hip/hip_runtime.h>
#include <stdint.h>

// MultiHeadAttention: B=2, S=2048, D=1024, H=16, Dh=64. fp32 in/out, bf16 MFMA inside.
// R20: restore champion. R19's KVBLK=256 attn spilled (launch_bounds(512,4) pins
// 64 VGPR; kv[4]/vv[4] prefetch exceeded it -> WRITE_SIZE 323MB scratch, attn
// 134us). attn reverted to R18 exactly (KVBLK=128, Q-direct, 34KB LDS, 54.8us).
// gemm2 kept at 128x64 from R19 (bundle attribution: ~-3us, risk-free).
// Carried: XCD swizzle everywhere, Q pre-scale, raw v_exp_f32, v_perm P-pack,
// fused V-transpose, 128x64 QKV GEMM.

typedef unsigned short u16;
typedef short s16x8 __attribute__((ext_vector_type(8)));   // 8 bf16 (4 VGPR)
typedef short s16x4 __attribute__((ext_vector_type(4)));   // 4 bf16 (2 VGPR)
typedef float f32x4 __attribute__((ext_vector_type(4)));
typedef u16 u16x4 __attribute__((ext_vector_type(4)));

#define S_LEN 2048
#define DMODEL 1024
#define LOG2E 1.44269504088896340736f

__device__ __forceinline__ u16 f2bf(float f) {
  union { float f; uint32_t u; } v; v.f = f;
  return (u16)((v.u + 0x8000u) >> 16);
}

__device__ __forceinline__ s16x8 ld8f(const float* s) {  // 8 fp32 -> 8 bf16
  f32x4 a = *(const f32x4*)s;
  f32x4 b = *(const f32x4*)(s + 4);
  s16x8 r;
  r[0] = (short)f2bf(a[0]); r[1] = (short)f2bf(a[1]);
  r[2] = (short)f2bf(a[2]); r[3] = (short)f2bf(a[3]);
  r[4] = (short)f2bf(b[0]); r[5] = (short)f2bf(b[1]);
  r[6] = (short)f2bf(b[2]); r[7] = (short)f2bf(b[3]);
  return r;
}

// async global->LDS, 16B/lane; HW scatters lane i to ldsbase + i*16
__device__ __forceinline__ void gl2lds16(const u16* g, u16* l) {
  __builtin_amdgcn_global_load_lds(
      (const __attribute__((address_space(1))) uint32_t*)g,
      (__attribute__((address_space(3))) uint32_t*)l, 16, 0, 0);
}

// ---------------------------------------------------------------------------
// fp32 -> bf16 conversion: 4 weights (1M elem) + 3 activations (4.19M elem).
// ---------------------------------------------------------------------------
struct Cvt7 { const float* s[7]; u16* d[7]; int n[7]; };

__global__ __launch_bounds__(256) void cvt7(Cvt7 p) {
  const int z = blockIdx.y;
  const int idx = blockIdx.x * 256 + threadIdx.x;
  if (idx * 8 < p.n[z])
    *(s16x8*)(p.d[z] + (size_t)idx * 8) = ld8f(p.s[z] + (size_t)idx * 8);
}

// ---------------------------------------------------------------------------
// GEMM: C[M,N] = (A[M,K] @ W[N,K]^T + bias[N]) * scl; A,W bf16, bias fp32.
// Template: BM x BN tile (BK=64 fixed), 4 waves as 2x2 of (BM/2 x BN/2).
// OUT_F32: fp32 C (O projection). VT: z==2 writes transposed bf16 to p.vt.
// XCD swizzle: lid = (w&7)*(nwg/8) + w/8 groups contiguous bm-rows per XCD.
// ---------------------------------------------------------------------------
struct GemmBatch {
  const u16* A[3]; const u16* W[3]; const float* Bv[3]; void* C[3];
  u16* vt;       // VT destination: Vt[(b*16+h)*64+dh][s], row stride S_LEN
  float scl[3];  // epilogue scale (fp32, applied before f2bf round)
};

template <int BM, int BN, bool OUT_F32, bool VT>
__global__ __launch_bounds__(256) void gemm_bt(GemmBatch p, int M, int N, int K) {
  static_assert(!VT || BM == 128, "VT epilogue assumes BM=128 (batch arith)");
  constexpr int MI = BM / 32, NJ = BN / 32;   // fragment repeats per wave
  constexpr int TS = BM + 8;                  // VT transpose stride (u16), 16B-aligned
  constexpr int AB = BM * 64 + BN * 64;
  constexpr int TB = VT ? BN * TS : 0;
  constexpr int SM = AB > TB ? AB : TB;
  __shared__ u16 smem[SM];
  u16* const As = smem;
  u16* const Ws = smem + BM * 64;

  const int z = blockIdx.z;
  const u16* __restrict__ A      = p.A[z];
  const u16* __restrict__ W      = p.W[z];
  const float* __restrict__ bias = p.Bv[z];
  const float scl = p.scl[z];

  const int tid = threadIdx.x;
  const int wave = tid >> 6, lane = tid & 63;
  const int quad = lane >> 4, l16 = lane & 15;

  // XCD-aware bijective swizzle (nwg divisible by 8 for all our grids)
  const int nwg = gridDim.x * gridDim.y;
  const int w = blockIdx.x + gridDim.x * blockIdx.y;
  const int lid = (w & 7) * (nwg >> 3) + (w >> 3);
  const int bm = (lid / gridDim.x) * BM, bn = (lid % gridDim.x) * BN;

  const int wr = (wave >> 1) * (BM / 2), wc = (wave & 1) * (BN / 2);
  const int sr8 = lane >> 3;
  const int slc = (lane & 7) ^ sr8;           // logical k-chunk to fetch
  const int srow = wave * 8 + sr8;            // row within 32-row stripe

  f32x4 acc[MI][NJ];
#pragma unroll
  for (int i = 0; i < MI; i++)
#pragma unroll
    for (int j = 0; j < NJ; j++) acc[i][j] = {0.f, 0.f, 0.f, 0.f};

  const u16* Ab = A + (size_t)bm * K;
  const u16* Wb = W + (size_t)bn * K;

  for (int kt = 0; kt < K; kt += 64) {
    __syncthreads();  // previous iteration's LDS reads complete
#pragma unroll
    for (int i = 0; i < MI; i++)
      gl2lds16(Ab + (size_t)(i * 32 + srow) * K + kt + slc * 8,
               &As[(i * 32 + wave * 8) * 64]);
#pragma unroll
    for (int i = 0; i < NJ; i++)
      gl2lds16(Wb + (size_t)(i * 32 + srow) * K + kt + slc * 8,
               &Ws[(i * 32 + wave * 8) * 64]);
    __syncthreads();  // drains vmcnt (async loads) + LDS visible

#pragma unroll
    for (int ks = 0; ks < 2; ks++) {
      const int ch = ks * 4 + quad;  // logical chunk of this fragment
      s16x8 a[MI], b[NJ];
#pragma unroll
      for (int t = 0; t < MI; t++)
        a[t] = *(const s16x8*)&As[(wr + t * 16 + l16) * 64 + ((ch ^ (l16 & 7)) << 3)];
#pragma unroll
      for (int t = 0; t < NJ; t++)
        b[t] = *(const s16x8*)&Ws[(wc + t * 16 + l16) * 64 + ((ch ^ (l16 & 7)) << 3)];
#pragma unroll
      for (int i = 0; i < MI; i++)
#pragma unroll
        for (int j = 0; j < NJ; j++)
          acc[i][j] = __builtin_amdgcn_mfma_f32_16x16x32_bf16(a[i], b[j], acc[i][j], 0, 0, 0);
    }
  }

  if (VT && z == 2) {
    // ---- fused V transpose: acc -> LDS [col][row] -> Vt[d-row][s] ----
    __syncthreads();               // all waves done reading As/Ws
    u16* const T = smem;           // [BN][TS]
#pragma unroll
    for (int j = 0; j < NJ; j++) {
      const int c = wc + j * 16 + l16;
      const float bv = bias[bn + c];
#pragma unroll
      for (int i = 0; i < MI; i++) {
        const int r0 = wr + i * 16 + quad * 4;
        u16x4 t4;
#pragma unroll
        for (int r = 0; r < 4; r++) t4[r] = f2bf((acc[i][j][r] + bv) * scl);
        *(u16x4*)&T[c * TS + r0] = t4;
      }
    }
    __syncthreads();
    // copy out: SEG threads per column, run = BM/SEG contiguous s per thread
    constexpr int SEG = 256 / BN;            // 2 (BN=128) or 4 (BN=64)
    constexpr int RUN = BM / SEG;            // 64 or 32
    const int c = tid / SEG, seg = tid % SEG;
    const int b_ = bm >> 11;                 // batch (2048 rows each, 128 | 2048)
    const int sb = (bm & 2047) + seg * RUN;  // s within batch
    u16* dst = p.vt + (size_t)(b_ * 1024 + bn + c) * S_LEN + sb;
    const u16* srcT = &T[c * TS + seg * RUN];
#pragma unroll
    for (int k = 0; k < RUN / 8; k++)
      *(s16x8*)(dst + k * 8) = *(const s16x8*)(srcT + k * 8);
  } else {
    // epilogue: C/D layout row = quad*4 + reg, col = lane&15
#pragma unroll
    for (int j = 0; j < NJ; j++) {
      const int col = bn + wc + j * 16 + l16;
      const float bv = bias[col];
#pragma unroll
      for (int i = 0; i < MI; i++) {
        const int row0 = bm + wr + i * 16 + quad * 4;
#pragma unroll
        for (int r = 0; r < 4; r++) {
          const float val = (acc[i][j][r] + bv) * scl;
          if (OUT_F32)
            ((float*)p.C[z])[(size_t)(row0 + r) * N + col] = val;
          else
            ((u16*)p.C[z])[(size_t)(row0 + r) * N + col] = f2bf(val);
        }
      }
    }
  }
}

// ---------------------------------------------------------------------------
// Flash attention (R18, proven 54.8us): 512 threads = 8 waves = 4 q-tiles
// (32 rows) x 2 kv-halves(64 kv). KVBLK=128. Q fragments direct from global.
// LDS 34KB (Ks 16 + Vs 16; merge overlays). Grid (16,32), XCD swizzle.
// ---------------------------------------------------------------------------
__global__ __launch_bounds__(512, 4) void attn_kernel(const u16* __restrict__ Qp,
                                                      const u16* __restrict__ Kp,
                                                      const u16* __restrict__ Vt,
                                                      u16* __restrict__ AO) {
  __shared__ u16 smem[17408];    // 34 KB (16 Ks + 16 Vs; merge overlays 34)
  u16* const Ks = smem;          // [kv:128][d:64] 16 KB, 8-chunk XOR swizzle
  u16* const Vs = smem + 8192;   // [d:64][kv:128] 16 KB, 16-chunk XOR swizzle

  const int tid = threadIdx.x;
  const int wave = tid >> 6, lane = tid & 63;
  const int quad = lane >> 4, l16 = lane & 15;

  // XCD swizzle: w = x + 16y, nwg=512 -> 64 lids/XCD -> bh in [4j,4j+4)
  const int w = blockIdx.x + gridDim.x * blockIdx.y;
  const int lid = (w & 7) * 64 + (w >> 3);
  const int bh = lid >> 4, b = bh >> 4, h = bh & 15;
  const int s0 = (lid & 15) * 128;

  const int qw = wave & 3;        // q-tile index (32 rows each)
  const int kvh = wave >> 2;      // kv half (64 kv rows each)

  const int sr = tid >> 3, sc8 = tid & 7;
  const int sxor = (sc8 ^ (sr & 7)) << 3;
  const int vr = tid >> 4, vc = tid & 15;
  const int vxor = (vc ^ (vr & 15)) << 3;

  // ---- Q fragments: direct global load (same values staging delivered) ----
  s16x8 aq[2][2];  // [ks][rt]
#pragma unroll
  for (int ks = 0; ks < 2; ks++)
#pragma unroll
    for (int rt = 0; rt < 2; rt++) {
      const int row = qw * 32 + rt * 16 + l16;
      const int ch = ks * 4 + quad;
      aq[ks][rt] = *(const s16x8*)(Qp + (size_t)(b * S_LEN + s0 + row) * DMODEL + h * 64 + ch * 8);
    }

  // ---- K/V register prefetch for kt=0 (cooperative staging) ----
  s16x8 kv[2], vv[2];
#pragma unroll
  for (int i = 0; i < 2; i++)
    kv[i] = *(const s16x8*)(Kp + (size_t)(b * S_LEN + i * 64 + sr) * DMODEL + h * 64 + sc8 * 8);
#pragma unroll
  for (int i = 0; i < 2; i++)
    vv[i] = *(const s16x8*)(Vt + (size_t)(bh * 64 + i * 32 + vr) * S_LEN + vc * 8);

  f32x4 o[2][4];
  float l_r[2] = {0.f, 0.f};
#pragma unroll
  for (int rt = 0; rt < 2; rt++)
#pragma unroll
    for (int dt = 0; dt < 4; dt++) o[rt][dt] = {0.f, 0.f, 0.f, 0.f};

  const f32x4 zf = {0.f, 0.f, 0.f, 0.f};

  for (int kt = 0; kt < S_LEN; kt += 128) {
    __syncthreads();
#pragma unroll
    for (int i = 0; i < 2; i++)
      *(s16x8*)&Ks[(i * 64 + sr) * 64 + sxor] = kv[i];
#pragma unroll
    for (int i = 0; i < 2; i++)
      *(s16x8*)&Vs[(i * 32 + vr) * 128 + vxor] = vv[i];
    __syncthreads();

    if (kt + 128 < S_LEN) {
      const int k2 = kt + 128;
#pragma unroll
      for (int i = 0; i < 2; i++)
        kv[i] = *(const s16x8*)(Kp + (size_t)(b * S_LEN + k2 + i * 64 + sr) * DMODEL + h * 64 + sc8 * 8);
#pragma unroll
      for (int i = 0; i < 2; i++)
        vv[i] = *(const s16x8*)(Vt + (size_t)(bh * 64 + i * 32 + vr) * S_LEN + k2 + vc * 8);
    }

    // this wave's kv half: rows kvh*64 .. kvh*64+63 (4 subtiles of 16)
#pragma unroll
    for (int kvt = 0; kvt < 4; kvt++) {
      const int krow = kvh * 64 + kvt * 16 + l16;   // krow&7 == l16&7
      s16x8 ak0 = *(const s16x8*)&Ks[krow * 64 + (((0 + quad) ^ (l16 & 7)) << 3)];
      s16x8 ak1 = *(const s16x8*)&Ks[krow * 64 + (((4 + quad) ^ (l16 & 7)) << 3)];

      s16x4 pf[2];
#pragma unroll
      for (int rt = 0; rt < 2; rt++) {
        f32x4 sA;
        sA = __builtin_amdgcn_mfma_f32_16x16x32_bf16(ak0, aq[0][rt], zf, 0, 0, 0);
        sA = __builtin_amdgcn_mfma_f32_16x16x32_bf16(ak1, aq[1][rt], sA, 0, 0, 0);

        union { float f; uint32_t u; } e0, e1, e2, e3;
        e0.f = __builtin_amdgcn_exp2f(sA[0]);
        e1.f = __builtin_amdgcn_exp2f(sA[1]);
        e2.f = __builtin_amdgcn_exp2f(sA[2]);
        e3.f = __builtin_amdgcn_exp2f(sA[3]);
        l_r[rt] += (((e0.f + e1.f) + e2.f) + e3.f);

        union { uint32_t u[2]; s16x4 v; } pk;
        pk.u[0] = __builtin_amdgcn_perm(e1.u + 0x8000u, e0.u + 0x8000u, 0x07060302u);
        pk.u[1] = __builtin_amdgcn_perm(e3.u + 0x8000u, e2.u + 0x8000u, 0x07060302u);
        pf[rt] = pk.v;
      }

      const int ch = kvh * 8 + kvt * 2 + (quad >> 1);
#pragma unroll
      for (int dt = 0; dt < 4; dt++) {
        const int row = dt * 16 + l16;
        s16x4 bv = *(const s16x4*)&Vs[row * 128 + ((ch ^ l16) << 3) + (quad & 1) * 4];
        o[0][dt] = __builtin_amdgcn_mfma_f32_16x16x16bf16_1k(pf[0], bv, o[0][dt], 0, 0, 0);
        o[1][dt] = __builtin_amdgcn_mfma_f32_16x16x16bf16_1k(pf[1], bv, o[1][dt], 0, 0, 0);
      }
    }
  }

  // intra-wave l reduction (sum over quads -> value depends on l16 only)
#pragma unroll
  for (int rt = 0; rt < 2; rt++) {
    l_r[rt] += __shfl_xor(l_r[rt], 16);
    l_r[rt] += __shfl_xor(l_r[rt], 32);
  }

  // ---- cross-half merge: waves 4..7 dump O/l into reused staging LDS ----
  __syncthreads();  // all LDS reads of last ktile complete
  f32x4* const mrgO = (f32x4*)smem;            // [rt*4+dt][w*64+lane], 32 KB
  float* const mrgL = (float*)smem + 8192;     // [rt][w*64+lane], 2 KB @ 32 KB
  if (wave >= 4) {
    const int w4 = wave - 4;
#pragma unroll
    for (int rt = 0; rt < 2; rt++) {
#pragma unroll
      for (int dt = 0; dt < 4; dt++)
        mrgO[(rt * 4 + dt) * 256 + w4 * 64 + lane] = o[rt][dt];
      mrgL[rt * 256 + w4 * 64 + lane] = l_r[rt];
    }
  }
  __syncthreads();
  if (wave < 4) {
#pragma unroll
    for (int rt = 0; rt < 2; rt++) {
#pragma unroll
      for (int dt = 0; dt < 4; dt++) {
        f32x4 ov = mrgO[(rt * 4 + dt) * 256 + wave * 64 + lane];
        o[rt][dt] += ov;
      }
      l_r[rt] += mrgL[rt * 256 + wave * 64 + lane];
    }
#pragma unroll
    for (int rt = 0; rt < 2; rt++) {
#pragma unroll
      for (int r = 0; r < 4; r++) {
        const float linv = 1.f / __shfl(l_r[rt], quad * 4 + r);
        const int row = s0 + qw * 32 + rt * 16 + quad * 4 + r;
#pragma unroll
        for (int dt = 0; dt < 4; dt++)
          AO[(size_t)(b * S_LEN + row) * DMODEL + h * 64 + dt * 16 + l16] =
              f2bf(o[rt][dt][r] * linv);
      }
    }
  }
}

// ---------------------------------------------------------------------------
extern "C" void kernel_launch(void* const* d_in, const int* in_sizes, int n_in,
                              void* d_out, int out_size, void* d_ws, size_t ws_size,
                              hipStream_t stream) {
  const float* query = (const float*)d_in[0];
  const float* key_  = (const float*)d_in[1];
  const float* value = (const float*)d_in[2];
  const float* W_q = (const float*)d_in[3];
  const float* b_q = (const float*)d_in[4];
  const float* W_k = (const float*)d_in[5];
  const float* b_k = (const float*)d_in[6];
  const float* W_v = (const float*)d_in[7];
  const float* b_v = (const float*)d_in[8];
  const float* W_o = (const float*)d_in[9];
  const float* b_o = (const float*)d_in[10];
  float* out = (float*)d_out;

  const int M = 2 * S_LEN;  // 4096
  const int N = DMODEL, K = DMODEL;
  const size_t WSZ = (size_t)DMODEL * DMODEL;   // 1,048,576
  const size_t SZ  = (size_t)M * DMODEL;        // 4,194,304

  u16* Wqb = (u16*)d_ws;         // 4 bf16 weights
  u16* Wkb = Wqb + WSZ;
  u16* Wvb = Wkb + WSZ;
  u16* Wob = Wvb + WSZ;
  u16* Qa  = Wob + WSZ;          // bf16 inputs (dead after QKV GEMM)
  u16* Ka  = Qa + SZ;
  u16* Va  = Ka + SZ;
  u16* Qp  = Va + SZ;            // projections
  u16* Kp  = Qp + SZ;
  u16* Vt  = Kp + SZ;            // [B,H,Dh,S] -- written directly by V-GEMM (VT path)
  u16* AO  = Qp;                 // aliases Qp (per-block disjoint read->write)

  Cvt7 cw;
  cw.s[0] = W_q;   cw.d[0] = Wqb; cw.n[0] = (int)WSZ;
  cw.s[1] = W_k;   cw.d[1] = Wkb; cw.n[1] = (int)WSZ;
  cw.s[2] = W_v;   cw.d[2] = Wvb; cw.n[2] = (int)WSZ;
  cw.s[3] = W_o;   cw.d[3] = Wob; cw.n[3] = (int)WSZ;
  cw.s[4] = query; cw.d[4] = Qa;  cw.n[4] = (int)SZ;
  cw.s[5] = key_;  cw.d[5] = Ka;  cw.n[5] = (int)SZ;
  cw.s[6] = value; cw.d[6] = Va;  cw.n[6] = (int)SZ;
  cvt7<<<dim3((int)(SZ / 2048), 7), 256, 0, stream>>>(cw);

  GemmBatch p1;
  p1.A[0] = Qa; p1.W[0] = Wqb; p1.Bv[0] = b_q; p1.C[0] = Qp;
  p1.A[1] = Ka; p1.W[1] = Wkb; p1.Bv[1] = b_k; p1.C[1] = Kp;
  p1.A[2] = Va; p1.W[2] = Wvb; p1.Bv[2] = b_v; p1.C[2] = Vt;  // unused (VT path)
  p1.vt = Vt;
  p1.scl[0] = 0.03125f * LOG2E;  // d_model^-0.5 * log2(e) folded into Q (fp32)
  p1.scl[1] = 1.0f;
  p1.scl[2] = 1.0f;
  gemm_bt<128, 64, false, true><<<dim3(N / 64, M / 128, 3), 256, 0, stream>>>(p1, M, N, K);

  attn_kernel<<<dim3(S_LEN / 128, 32), 512, 0, stream>>>(Qp, Kp, Vt, AO);

  GemmBatch p2;
  p2.A[0] = AO; p2.W[0] = Wob; p2.Bv[0] = b_o; p2.C[0] = out;
  p2.A[1] = AO; p2.W[1] = Wob; p2.Bv[1] = b_o; p2.C[1] = out;
  p2.A[2] = AO; p2.W[2] = Wob; p2.Bv[2] = b_o; p2.C[2] = out;
  p2.vt = nullptr;
  p2.scl[0] = 1.0f; p2.scl[1] = 1.0f; p2.scl[2] = 1.0f;
  gemm_bt<128, 64, true, false><<<dim3(N / 64, M / 128, 1), 256, 0, stream>>>(p2, M, N, K);
}

// Round 14
// 218.704 us; speedup vs baseline: 1.3532x; 1.0263x over previous
//
#include <hip/hip_runtime.h>
#include <stdint.h>

// MultiHeadAttention: B=2, S=2048, D=1024, H=16, Dh=64. fp32 in/out, bf16 MFMA inside.
// R21: restore R18 champion exactly (gemm2 back to 64x64 — R20's clean A/B showed
// the 128x64 retile cost +5us; this problem's kernels are uniformly TLP-hungry).
// One micro-change: cvt7 grid compaction. Old (2048,7) grid had 6144/14336 blocks
// idle (weights need 512 x-blocks). Total work = 2^24 elements = 8192 full blocks;
// 1D grid + shift-decode (all sizes pow2) removes idle blocks and bounds check.
// Bit-identical conversions.
// Carried: XCD swizzle everywhere, Q pre-scale, raw v_exp_f32, v_perm P-pack,
// fused V-transpose, 128x64 QKV GEMM, Q-direct attn fragments.

typedef unsigned short u16;
typedef short s16x8 __attribute__((ext_vector_type(8)));   // 8 bf16 (4 VGPR)
typedef short s16x4 __attribute__((ext_vector_type(4)));   // 4 bf16 (2 VGPR)
typedef float f32x4 __attribute__((ext_vector_type(4)));
typedef u16 u16x4 __attribute__((ext_vector_type(4)));

#define S_LEN 2048
#define DMODEL 1024
#define LOG2E 1.44269504088896340736f

__device__ __forceinline__ u16 f2bf(float f) {
  union { float f; uint32_t u; } v; v.f = f;
  return (u16)((v.u + 0x8000u) >> 16);
}

__device__ __forceinline__ s16x8 ld8f(const float* s) {  // 8 fp32 -> 8 bf16
  f32x4 a = *(const f32x4*)s;
  f32x4 b = *(const f32x4*)(s + 4);
  s16x8 r;
  r[0] = (short)f2bf(a[0]); r[1] = (short)f2bf(a[1]);
  r[2] = (short)f2bf(a[2]); r[3] = (short)f2bf(a[3]);
  r[4] = (short)f2bf(b[0]); r[5] = (short)f2bf(b[1]);
  r[6] = (short)f2bf(b[2]); r[7] = (short)f2bf(b[3]);
  return r;
}

// async global->LDS, 16B/lane; HW scatters lane i to ldsbase + i*16
__device__ __forceinline__ void gl2lds16(const u16* g, u16* l) {
  __builtin_amdgcn_global_load_lds(
      (const __attribute__((address_space(1))) uint32_t*)g,
      (__attribute__((address_space(3))) uint32_t*)l, 16, 0, 0);
}

// ---------------------------------------------------------------------------
// fp32 -> bf16 conversion: 4 weights (2^20 elem each) + 3 activations (2^22).
// 1D grid, 8192 full blocks; shift-based (z, offset) decode (block-uniform z).
// ---------------------------------------------------------------------------
struct Cvt7 { const float* s[7]; u16* d[7]; };

__global__ __launch_bounds__(256) void cvt7(Cvt7 p) {
  const uint32_t g = blockIdx.x * 256 + threadIdx.x;  // chunk id (8 elem/chunk)
  int z;
  uint32_t off;
  if (g < (4u << 17)) {            // weights: 2^17 chunks each
    z = (int)(g >> 17);
    off = (g & ((1u << 17) - 1)) * 8;
  } else {                         // activations: 2^19 chunks each
    const uint32_t g2 = g - (4u << 17);
    z = 4 + (int)(g2 >> 19);
    off = (g2 & ((1u << 19) - 1)) * 8;
  }
  *(s16x8*)(p.d[z] + off) = ld8f(p.s[z] + off);
}

// ---------------------------------------------------------------------------
// GEMM: C[M,N] = (A[M,K] @ W[N,K]^T + bias[N]) * scl; A,W bf16, bias fp32.
// Template: BM x BN tile (BK=64 fixed), 4 waves as 2x2 of (BM/2 x BN/2).
// OUT_F32: fp32 C (O projection). VT: z==2 writes transposed bf16 to p.vt.
// XCD swizzle: lid = (w&7)*(nwg/8) + w/8 groups contiguous bm-rows per XCD.
// ---------------------------------------------------------------------------
struct GemmBatch {
  const u16* A[3]; const u16* W[3]; const float* Bv[3]; void* C[3];
  u16* vt;       // VT destination: Vt[(b*16+h)*64+dh][s], row stride S_LEN
  float scl[3];  // epilogue scale (fp32, applied before f2bf round)
};

template <int BM, int BN, bool OUT_F32, bool VT>
__global__ __launch_bounds__(256) void gemm_bt(GemmBatch p, int M, int N, int K) {
  static_assert(!VT || BM == 128, "VT epilogue assumes BM=128 (batch arith)");
  constexpr int MI = BM / 32, NJ = BN / 32;   // fragment repeats per wave
  constexpr int TS = BM + 8;                  // VT transpose stride (u16), 16B-aligned
  constexpr int AB = BM * 64 + BN * 64;
  constexpr int TB = VT ? BN * TS : 0;
  constexpr int SM = AB > TB ? AB : TB;
  __shared__ u16 smem[SM];
  u16* const As = smem;
  u16* const Ws = smem + BM * 64;

  const int z = blockIdx.z;
  const u16* __restrict__ A      = p.A[z];
  const u16* __restrict__ W      = p.W[z];
  const float* __restrict__ bias = p.Bv[z];
  const float scl = p.scl[z];

  const int tid = threadIdx.x;
  const int wave = tid >> 6, lane = tid & 63;
  const int quad = lane >> 4, l16 = lane & 15;

  // XCD-aware bijective swizzle (nwg divisible by 8 for all our grids)
  const int nwg = gridDim.x * gridDim.y;
  const int w = blockIdx.x + gridDim.x * blockIdx.y;
  const int lid = (w & 7) * (nwg >> 3) + (w >> 3);
  const int bm = (lid / gridDim.x) * BM, bn = (lid % gridDim.x) * BN;

  const int wr = (wave >> 1) * (BM / 2), wc = (wave & 1) * (BN / 2);
  const int sr8 = lane >> 3;
  const int slc = (lane & 7) ^ sr8;           // logical k-chunk to fetch
  const int srow = wave * 8 + sr8;            // row within 32-row stripe

  f32x4 acc[MI][NJ];
#pragma unroll
  for (int i = 0; i < MI; i++)
#pragma unroll
    for (int j = 0; j < NJ; j++) acc[i][j] = {0.f, 0.f, 0.f, 0.f};

  const u16* Ab = A + (size_t)bm * K;
  const u16* Wb = W + (size_t)bn * K;

  for (int kt = 0; kt < K; kt += 64) {
    __syncthreads();  // previous iteration's LDS reads complete
#pragma unroll
    for (int i = 0; i < MI; i++)
      gl2lds16(Ab + (size_t)(i * 32 + srow) * K + kt + slc * 8,
               &As[(i * 32 + wave * 8) * 64]);
#pragma unroll
    for (int i = 0; i < NJ; i++)
      gl2lds16(Wb + (size_t)(i * 32 + srow) * K + kt + slc * 8,
               &Ws[(i * 32 + wave * 8) * 64]);
    __syncthreads();  // drains vmcnt (async loads) + LDS visible

#pragma unroll
    for (int ks = 0; ks < 2; ks++) {
      const int ch = ks * 4 + quad;  // logical chunk of this fragment
      s16x8 a[MI], b[NJ];
#pragma unroll
      for (int t = 0; t < MI; t++)
        a[t] = *(const s16x8*)&As[(wr + t * 16 + l16) * 64 + ((ch ^ (l16 & 7)) << 3)];
#pragma unroll
      for (int t = 0; t < NJ; t++)
        b[t] = *(const s16x8*)&Ws[(wc + t * 16 + l16) * 64 + ((ch ^ (l16 & 7)) << 3)];
#pragma unroll
      for (int i = 0; i < MI; i++)
#pragma unroll
        for (int j = 0; j < NJ; j++)
          acc[i][j] = __builtin_amdgcn_mfma_f32_16x16x32_bf16(a[i], b[j], acc[i][j], 0, 0, 0);
    }
  }

  if (VT && z == 2) {
    // ---- fused V transpose: acc -> LDS [col][row] -> Vt[d-row][s] ----
    __syncthreads();               // all waves done reading As/Ws
    u16* const T = smem;           // [BN][TS]
#pragma unroll
    for (int j = 0; j < NJ; j++) {
      const int c = wc + j * 16 + l16;
      const float bv = bias[bn + c];
#pragma unroll
      for (int i = 0; i < MI; i++) {
        const int r0 = wr + i * 16 + quad * 4;
        u16x4 t4;
#pragma unroll
        for (int r = 0; r < 4; r++) t4[r] = f2bf((acc[i][j][r] + bv) * scl);
        *(u16x4*)&T[c * TS + r0] = t4;
      }
    }
    __syncthreads();
    // copy out: SEG threads per column, run = BM/SEG contiguous s per thread
    constexpr int SEG = 256 / BN;            // 2 (BN=128) or 4 (BN=64)
    constexpr int RUN = BM / SEG;            // 64 or 32
    const int c = tid / SEG, seg = tid % SEG;
    const int b_ = bm >> 11;                 // batch (2048 rows each, 128 | 2048)
    const int sb = (bm & 2047) + seg * RUN;  // s within batch
    u16* dst = p.vt + (size_t)(b_ * 1024 + bn + c) * S_LEN + sb;
    const u16* srcT = &T[c * TS + seg * RUN];
#pragma unroll
    for (int k = 0; k < RUN / 8; k++)
      *(s16x8*)(dst + k * 8) = *(const s16x8*)(srcT + k * 8);
  } else {
    // epilogue: C/D layout row = quad*4 + reg, col = lane&15
#pragma unroll
    for (int j = 0; j < NJ; j++) {
      const int col = bn + wc + j * 16 + l16;
      const float bv = bias[col];
#pragma unroll
      for (int i = 0; i < MI; i++) {
        const int row0 = bm + wr + i * 16 + quad * 4;
#pragma unroll
        for (int r = 0; r < 4; r++) {
          const float val = (acc[i][j][r] + bv) * scl;
          if (OUT_F32)
            ((float*)p.C[z])[(size_t)(row0 + r) * N + col] = val;
          else
            ((u16*)p.C[z])[(size_t)(row0 + r) * N + col] = f2bf(val);
        }
      }
    }
  }
}

// ---------------------------------------------------------------------------
// Flash attention (R18, proven 54.8us): 512 threads = 8 waves = 4 q-tiles
// (32 rows) x 2 kv-halves(64 kv). KVBLK=128. Q fragments direct from global.
// LDS 34KB (Ks 16 + Vs 16; merge overlays). Grid (16,32), XCD swizzle.
// ---------------------------------------------------------------------------
__global__ __launch_bounds__(512, 4) void attn_kernel(const u16* __restrict__ Qp,
                                                      const u16* __restrict__ Kp,
                                                      const u16* __restrict__ Vt,
                                                      u16* __restrict__ AO) {
  __shared__ u16 smem[17408];    // 34 KB (16 Ks + 16 Vs; merge overlays 34)
  u16* const Ks = smem;          // [kv:128][d:64] 16 KB, 8-chunk XOR swizzle
  u16* const Vs = smem + 8192;   // [d:64][kv:128] 16 KB, 16-chunk XOR swizzle

  const int tid = threadIdx.x;
  const int wave = tid >> 6, lane = tid & 63;
  const int quad = lane >> 4, l16 = lane & 15;

  // XCD swizzle: w = x + 16y, nwg=512 -> 64 lids/XCD -> bh in [4j,4j+4)
  const int w = blockIdx.x + gridDim.x * blockIdx.y;
  const int lid = (w & 7) * 64 + (w >> 3);
  const int bh = lid >> 4, b = bh >> 4, h = bh & 15;
  const int s0 = (lid & 15) * 128;

  const int qw = wave & 3;        // q-tile index (32 rows each)
  const int kvh = wave >> 2;      // kv half (64 kv rows each)

  const int sr = tid >> 3, sc8 = tid & 7;
  const int sxor = (sc8 ^ (sr & 7)) << 3;
  const int vr = tid >> 4, vc = tid & 15;
  const int vxor = (vc ^ (vr & 15)) << 3;

  // ---- Q fragments: direct global load (same values staging delivered) ----
  s16x8 aq[2][2];  // [ks][rt]
#pragma unroll
  for (int ks = 0; ks < 2; ks++)
#pragma unroll
    for (int rt = 0; rt < 2; rt++) {
      const int row = qw * 32 + rt * 16 + l16;
      const int ch = ks * 4 + quad;
      aq[ks][rt] = *(const s16x8*)(Qp + (size_t)(b * S_LEN + s0 + row) * DMODEL + h * 64 + ch * 8);
    }

  // ---- K/V register prefetch for kt=0 (cooperative staging) ----
  s16x8 kv[2], vv[2];
#pragma unroll
  for (int i = 0; i < 2; i++)
    kv[i] = *(const s16x8*)(Kp + (size_t)(b * S_LEN + i * 64 + sr) * DMODEL + h * 64 + sc8 * 8);
#pragma unroll
  for (int i = 0; i < 2; i++)
    vv[i] = *(const s16x8*)(Vt + (size_t)(bh * 64 + i * 32 + vr) * S_LEN + vc * 8);

  f32x4 o[2][4];
  float l_r[2] = {0.f, 0.f};
#pragma unroll
  for (int rt = 0; rt < 2; rt++)
#pragma unroll
    for (int dt = 0; dt < 4; dt++) o[rt][dt] = {0.f, 0.f, 0.f, 0.f};

  const f32x4 zf = {0.f, 0.f, 0.f, 0.f};

  for (int kt = 0; kt < S_LEN; kt += 128) {
    __syncthreads();
#pragma unroll
    for (int i = 0; i < 2; i++)
      *(s16x8*)&Ks[(i * 64 + sr) * 64 + sxor] = kv[i];
#pragma unroll
    for (int i = 0; i < 2; i++)
      *(s16x8*)&Vs[(i * 32 + vr) * 128 + vxor] = vv[i];
    __syncthreads();

    if (kt + 128 < S_LEN) {
      const int k2 = kt + 128;
#pragma unroll
      for (int i = 0; i < 2; i++)
        kv[i] = *(const s16x8*)(Kp + (size_t)(b * S_LEN + k2 + i * 64 + sr) * DMODEL + h * 64 + sc8 * 8);
#pragma unroll
      for (int i = 0; i < 2; i++)
        vv[i] = *(const s16x8*)(Vt + (size_t)(bh * 64 + i * 32 + vr) * S_LEN + k2 + vc * 8);
    }

    // this wave's kv half: rows kvh*64 .. kvh*64+63 (4 subtiles of 16)
#pragma unroll
    for (int kvt = 0; kvt < 4; kvt++) {
      const int krow = kvh * 64 + kvt * 16 + l16;   // krow&7 == l16&7
      s16x8 ak0 = *(const s16x8*)&Ks[krow * 64 + (((0 + quad) ^ (l16 & 7)) << 3)];
      s16x8 ak1 = *(const s16x8*)&Ks[krow * 64 + (((4 + quad) ^ (l16 & 7)) << 3)];

      s16x4 pf[2];
#pragma unroll
      for (int rt = 0; rt < 2; rt++) {
        f32x4 sA;
        sA = __builtin_amdgcn_mfma_f32_16x16x32_bf16(ak0, aq[0][rt], zf, 0, 0, 0);
        sA = __builtin_amdgcn_mfma_f32_16x16x32_bf16(ak1, aq[1][rt], sA, 0, 0, 0);

        union { float f; uint32_t u; } e0, e1, e2, e3;
        e0.f = __builtin_amdgcn_exp2f(sA[0]);
        e1.f = __builtin_amdgcn_exp2f(sA[1]);
        e2.f = __builtin_amdgcn_exp2f(sA[2]);
        e3.f = __builtin_amdgcn_exp2f(sA[3]);
        l_r[rt] += (((e0.f + e1.f) + e2.f) + e3.f);

        union { uint32_t u[2]; s16x4 v; } pk;
        pk.u[0] = __builtin_amdgcn_perm(e1.u + 0x8000u, e0.u + 0x8000u, 0x07060302u);
        pk.u[1] = __builtin_amdgcn_perm(e3.u + 0x8000u, e2.u + 0x8000u, 0x07060302u);
        pf[rt] = pk.v;
      }

      const int ch = kvh * 8 + kvt * 2 + (quad >> 1);
#pragma unroll
      for (int dt = 0; dt < 4; dt++) {
        const int row = dt * 16 + l16;
        s16x4 bv = *(const s16x4*)&Vs[row * 128 + ((ch ^ l16) << 3) + (quad & 1) * 4];
        o[0][dt] = __builtin_amdgcn_mfma_f32_16x16x16bf16_1k(pf[0], bv, o[0][dt], 0, 0, 0);
        o[1][dt] = __builtin_amdgcn_mfma_f32_16x16x16bf16_1k(pf[1], bv, o[1][dt], 0, 0, 0);
      }
    }
  }

  // intra-wave l reduction (sum over quads -> value depends on l16 only)
#pragma unroll
  for (int rt = 0; rt < 2; rt++) {
    l_r[rt] += __shfl_xor(l_r[rt], 16);
    l_r[rt] += __shfl_xor(l_r[rt], 32);
  }

  // ---- cross-half merge: waves 4..7 dump O/l into reused staging LDS ----
  __syncthreads();  // all LDS reads of last ktile complete
  f32x4* const mrgO = (f32x4*)smem;            // [rt*4+dt][w*64+lane], 32 KB
  float* const mrgL = (float*)smem + 8192;     // [rt][w*64+lane], 2 KB @ 32 KB
  if (wave >= 4) {
    const int w4 = wave - 4;
#pragma unroll
    for (int rt = 0; rt < 2; rt++) {
#pragma unroll
      for (int dt = 0; dt < 4; dt++)
        mrgO[(rt * 4 + dt) * 256 + w4 * 64 + lane] = o[rt][dt];
      mrgL[rt * 256 + w4 * 64 + lane] = l_r[rt];
    }
  }
  __syncthreads();
  if (wave < 4) {
#pragma unroll
    for (int rt = 0; rt < 2; rt++) {
#pragma unroll
      for (int dt = 0; dt < 4; dt++) {
        f32x4 ov = mrgO[(rt * 4 + dt) * 256 + wave * 64 + lane];
        o[rt][dt] += ov;
      }
      l_r[rt] += mrgL[rt * 256 + wave * 64 + lane];
    }
#pragma unroll
    for (int rt = 0; rt < 2; rt++) {
#pragma unroll
      for (int r = 0; r < 4; r++) {
        const float linv = 1.f / __shfl(l_r[rt], quad * 4 + r);
        const int row = s0 + qw * 32 + rt * 16 + quad * 4 + r;
#pragma unroll
        for (int dt = 0; dt < 4; dt++)
          AO[(size_t)(b * S_LEN + row) * DMODEL + h * 64 + dt * 16 + l16] =
              f2bf(o[rt][dt][r] * linv);
      }
    }
  }
}

// ---------------------------------------------------------------------------
extern "C" void kernel_launch(void* const* d_in, const int* in_sizes, int n_in,
                              void* d_out, int out_size, void* d_ws, size_t ws_size,
                              hipStream_t stream) {
  const float* query = (const float*)d_in[0];
  const float* key_  = (const float*)d_in[1];
  const float* value = (const float*)d_in[2];
  const float* W_q = (const float*)d_in[3];
  const float* b_q = (const float*)d_in[4];
  const float* W_k = (const float*)d_in[5];
  const float* b_k = (const float*)d_in[6];
  const float* W_v = (const float*)d_in[7];
  const float* b_v = (const float*)d_in[8];
  const float* W_o = (const float*)d_in[9];
  const float* b_o = (const float*)d_in[10];
  float* out = (float*)d_out;

  const int M = 2 * S_LEN;  // 4096
  const int N = DMODEL, K = DMODEL;
  const size_t WSZ = (size_t)DMODEL * DMODEL;   // 1,048,576
  const size_t SZ  = (size_t)M * DMODEL;        // 4,194,304

  u16* Wqb = (u16*)d_ws;         // 4 bf16 weights
  u16* Wkb = Wqb + WSZ;
  u16* Wvb = Wkb + WSZ;
  u16* Wob = Wvb + WSZ;
  u16* Qa  = Wob + WSZ;          // bf16 inputs (dead after QKV GEMM)
  u16* Ka  = Qa + SZ;
  u16* Va  = Ka + SZ;
  u16* Qp  = Va + SZ;            // projections
  u16* Kp  = Qp + SZ;
  u16* Vt  = Kp + SZ;            // [B,H,Dh,S] -- written directly by V-GEMM (VT path)
  u16* AO  = Qp;                 // aliases Qp (per-block disjoint read->write)

  Cvt7 cw;
  cw.s[0] = W_q;   cw.d[0] = Wqb;
  cw.s[1] = W_k;   cw.d[1] = Wkb;
  cw.s[2] = W_v;   cw.d[2] = Wvb;
  cw.s[3] = W_o;   cw.d[3] = Wob;
  cw.s[4] = query; cw.d[4] = Qa;
  cw.s[5] = key_;  cw.d[5] = Ka;
  cw.s[6] = value; cw.d[6] = Va;
  cvt7<<<dim3(8192), 256, 0, stream>>>(cw);

  GemmBatch p1;
  p1.A[0] = Qa; p1.W[0] = Wqb; p1.Bv[0] = b_q; p1.C[0] = Qp;
  p1.A[1] = Ka; p1.W[1] = Wkb; p1.Bv[1] = b_k; p1.C[1] = Kp;
  p1.A[2] = Va; p1.W[2] = Wvb; p1.Bv[2] = b_v; p1.C[2] = Vt;  // unused (VT path)
  p1.vt = Vt;
  p1.scl[0] = 0.03125f * LOG2E;  // d_model^-0.5 * log2(e) folded into Q (fp32)
  p1.scl[1] = 1.0f;
  p1.scl[2] = 1.0f;
  gemm_bt<128, 64, false, true><<<dim3(N / 64, M / 128, 3), 256, 0, stream>>>(p1, M, N, K);

  attn_kernel<<<dim3(S_LEN / 128, 32), 512, 0, stream>>>(Qp, Kp, Vt, AO);

  GemmBatch p2;
  p2.A[0] = AO; p2.W[0] = Wob; p2.Bv[0] = b_o; p2.C[0] = out;
  p2.A[1] = AO; p2.W[1] = Wob; p2.Bv[1] = b_o; p2.C[1] = out;
  p2.A[2] = AO; p2.W[2] = Wob; p2.Bv[2] = b_o; p2.C[2] = out;
  p2.vt = nullptr;
  p2.scl[0] = 1.0f; p2.scl[1] = 1.0f; p2.scl[2] = 1.0f;
  gemm_bt<64, 64, true, false><<<dim3(N / 64, M / 64, 1), 256, 0, stream>>>(p2, M, N, K);
}